// Round 9
// baseline (381.402 us; speedup 1.0000x reference)
//
#include <hip/hip_runtime.h>
#include <hip/hip_cooperative_groups.h>
#include <math.h>

namespace cg = cooperative_groups;

#define N_NODES 10000
#define N_EDGES 160000
#define D 512
#define NB 512  // cooperative grid size (2 blocks/CU on 256 CUs)

struct MegaP {
    const float *x, *t, *w0, *b0, *w1, *b1;
    const float *W1i, *W1o, *W2i, *W2o;
    const float *b1i, *b1o, *b2i, *b2o, *fcw, *fcb;
    const int *ein, *eout;
    float* out;
    float2 *V, *U, *beta1, *cvec;
    float2 *r0, *r1, *p0, *p1;
    int *cnt0, *cnt1, *rowp0, *rowp1, *fpos0, *fpos1, *es0, *es1;
    float *dv0, *dv1;
};

__global__ __launch_bounds__(256, 2) void mega(MegaP p) {
    cg::grid_group grid = cg::this_grid();
    const int bid = blockIdx.x, tid = threadIdx.x;
    const int wave = tid >> 6, lane = tid & 63;
    __shared__ int wsum[4];

    // ================= Phase A: vproj (blocks 0..255) | zero cnt (256..511)
    if (bid < 256) {
        int wv = bid * 4 + wave;              // 0..1023
        int b = wv >> 9, k = wv & 511;
        const float* W = b ? p.W2o : p.W2i;
        const float* F = p.fcw + b * 1024;
        float v0 = 0.f, v1 = 0.f;
        for (int n = lane; n < 512; n += 64) {
            float w = W[k * 512 + n];
            v0 += w * F[2 * n];
            v1 += w * F[2 * n + 1];
        }
#pragma unroll
        for (int off = 32; off; off >>= 1) {
            v0 += __shfl_down(v0, off);
            v1 += __shfl_down(v1, off);
        }
        if (lane == 0) p.V[wv] = make_float2(v0, v1);
    } else {
        int i = (bid - 256) * 256 + tid;
        if (i < N_NODES) { p.cnt0[i] = 0; p.cnt1[i] = 0; }
    }
    grid.sync();

    // ================= Phase B: uproj (blocks 0..256) | degree (257..511)
    if (bid <= 256) {
        int wv = bid * 4 + wave;              // 0..1027
        if (wv < 1024) {
            int b = wv >> 9, j = wv & 511;
            const float* W = b ? p.W1o : p.W1i;
            const float2* Vb = p.V + b * 512;
            float u0 = 0.f, u1 = 0.f;
            for (int k = lane; k < 512; k += 64) {
                float w = W[j * 512 + k];
                float2 v = Vb[k];
                u0 += w * v.x;
                u1 += w * v.y;
            }
#pragma unroll
            for (int off = 32; off; off >>= 1) {
                u0 += __shfl_down(u0, off);
                u1 += __shfl_down(u1, off);
            }
            if (lane == 0) p.U[wv] = make_float2(u0, u1);
        } else if (wv == 1024) {
            float a00 = 0.f, a01 = 0.f, a10 = 0.f, a11 = 0.f, c0 = 0.f, c1 = 0.f;
            for (int k = lane; k < 512; k += 64) {
                float2 v0 = p.V[k], v1 = p.V[512 + k];
                a00 += p.b1i[k] * v0.x;
                a01 += p.b1i[k] * v0.y;
                a10 += p.b1o[k] * v1.x;
                a11 += p.b1o[k] * v1.y;
                c0 += p.b2i[k] * p.fcw[2 * k] + p.b2o[k] * p.fcw[2 * (512 + k)];
                c1 += p.b2i[k] * p.fcw[2 * k + 1] + p.b2o[k] * p.fcw[2 * (512 + k) + 1];
            }
#pragma unroll
            for (int off = 32; off; off >>= 1) {
                a00 += __shfl_down(a00, off);
                a01 += __shfl_down(a01, off);
                a10 += __shfl_down(a10, off);
                a11 += __shfl_down(a11, off);
                c0 += __shfl_down(c0, off);
                c1 += __shfl_down(c1, off);
            }
            if (lane == 0) {
                p.beta1[0] = make_float2(a00, a01);
                p.beta1[1] = make_float2(a10, a11);
                *p.cvec = make_float2(c0 + p.fcb[0], c1 + p.fcb[1]);
            }
        }
    } else {
        for (int i = (bid - 257) * 256 + tid; i < 2 * N_EDGES; i += 255 * 256) {
            int br = i >= N_EDGES;
            int e = i - br * N_EDGES;
            const int* ei = br ? p.eout : p.ein;
            atomicAdd(&(br ? p.cnt1 : p.cnt0)[ei[N_EDGES + e]], 1);
        }
    }
    grid.sync();

    // ================= Phase C: CSR scan + dinv (blocks 0,1) | r (2..511)
    if (bid < 2) {
        const int* cnt = bid ? p.cnt1 : p.cnt0;
        int* rowp = bid ? p.rowp1 : p.rowp0;
        int* fpos = bid ? p.fpos1 : p.fpos0;
        float* dv = bid ? p.dv1 : p.dv0;
        const int base = tid * 40;
        int sum = 0;
#pragma unroll 4
        for (int j = 0; j < 40; ++j) {
            int i = base + j;
            if (i < N_NODES) sum += cnt[i];
        }
        int incl = sum;
#pragma unroll
        for (int off = 1; off < 64; off <<= 1) {
            int n = __shfl_up(incl, off);
            if (lane >= off) incl += n;
        }
        if (lane == 63) wsum[wave] = incl;
        __syncthreads();
        int wo = 0;
        for (int w = 0; w < wave; ++w) wo += wsum[w];
        int run = wo + incl - sum;   // exclusive offset of this thread's chunk
#pragma unroll 4
        for (int j = 0; j < 40; ++j) {
            int i = base + j;
            if (i < N_NODES) {
                rowp[i] = run;
                fpos[i] = run;
                int c = cnt[i];
                dv[i] = rsqrtf((float)c + 1.0f);
                run += c;
            }
        }
        if (tid == 255) rowp[N_NODES] = run;
    } else {
        for (int node = (bid - 2) * 4 + wave; node < N_NODES; node += 510 * 4) {
            int j0 = lane * 8;
            float tv = p.t[node];
            float4 xa = *(const float4*)&p.x[(size_t)node * D + j0];
            float4 xb = *(const float4*)&p.x[(size_t)node * D + j0 + 4];
            float xv[8] = {xa.x, xa.y, xa.z, xa.w, xb.x, xb.y, xb.z, xb.w};
            float s00 = 0.f, s01 = 0.f, s10 = 0.f, s11 = 0.f;
#pragma unroll
            for (int j = 0; j < 8; ++j) {
                float xx = xv[j];
                float te0 = xx + __cosf(tv * p.w0[j0 + j] + p.b0[j0 + j]);
                float te1 = xx + __cosf(tv * p.w1[j0 + j] + p.b1[j0 + j]);
                float2 u0 = p.U[j0 + j];
                float2 u1 = p.U[512 + j0 + j];
                s00 += te0 * u0.x;
                s01 += te0 * u0.y;
                s10 += te1 * u1.x;
                s11 += te1 * u1.y;
            }
#pragma unroll
            for (int off = 32; off; off >>= 1) {
                s00 += __shfl_down(s00, off);
                s01 += __shfl_down(s01, off);
                s10 += __shfl_down(s10, off);
                s11 += __shfl_down(s11, off);
            }
            if (lane == 0) {
                p.r0[node] = make_float2(s00, s01);
                p.r1[node] = make_float2(s10, s11);
            }
        }
    }
    grid.sync();

    // ================= Phase D: CSR fill (all blocks; esrc only)
    for (int i = bid * 256 + tid; i < 2 * N_EDGES; i += NB * 256) {
        int br = i >= N_EDGES;
        int e = i - br * N_EDGES;
        const int* ei = br ? p.eout : p.ein;
        int s = ei[e], d = ei[N_EDGES + e];
        int pos = atomicAdd(&(br ? p.fpos1 : p.fpos0)[d], 1);
        (br ? p.es1 : p.es0)[pos] = s;
    }
    grid.sync();

    // ================= Phase E: p_full = Shat.r + beta1 (gather, wave/node)
    const int gw = bid * 4 + wave, NW = NB * 4;
    const int half = lane >> 5, hl = lane & 31;
    for (int node = gw; node < N_NODES; node += NW) {
        const int* rowp = half ? p.rowp1 : p.rowp0;
        const int* es = half ? p.es1 : p.es0;
        const float* dv = half ? p.dv1 : p.dv0;
        const float2* rr = half ? p.r1 : p.r0;
        int beg = rowp[node], end = rowp[node + 1];
        float a0 = 0.f, a1 = 0.f;
        for (int e = beg + hl; e < end; e += 32) {
            int s = es[e];
            float ds = dv[s];
            float2 rv = rr[s];
            a0 += ds * rv.x;
            a1 += ds * rv.y;
        }
#pragma unroll
        for (int m = 16; m; m >>= 1) {
            a0 += __shfl_xor(a0, m);
            a1 += __shfl_xor(a1, m);
        }
        float dvd = dv[node];
        float2 rv = rr[node];
        float2 bb = p.beta1[half];
        if (hl == 0) {
            (half ? p.p1 : p.p0)[node] = make_float2(
                dvd * a0 + dvd * dvd * rv.x + bb.x,
                dvd * a1 + dvd * dvd * rv.y + bb.y);
        }
    }
    grid.sync();

    // ================= Phase F: z = Shat.p + cvec ; log_softmax
    for (int node = gw; node < N_NODES; node += NW) {
        const int* rowp = half ? p.rowp1 : p.rowp0;
        const int* es = half ? p.es1 : p.es0;
        const float* dv = half ? p.dv1 : p.dv0;
        const float2* pp = half ? p.p1 : p.p0;
        int beg = rowp[node], end = rowp[node + 1];
        float a0 = 0.f, a1 = 0.f;
        for (int e = beg + hl; e < end; e += 32) {
            int s = es[e];
            float ds = dv[s];
            float2 pv = pp[s];
            a0 += ds * pv.x;
            a1 += ds * pv.y;
        }
#pragma unroll
        for (int m = 16; m; m >>= 1) {
            a0 += __shfl_xor(a0, m);
            a1 += __shfl_xor(a1, m);
        }
        float dvd = dv[node];
        float2 pself = pp[node];
        a0 = dvd * a0 + dvd * dvd * pself.x;
        a1 = dvd * a1 + dvd * dvd * pself.y;
        a0 += __shfl_xor(a0, 32);
        a1 += __shfl_xor(a1, 32);
        if (lane == 0) {
            float2 cv = *p.cvec;
            float z0 = a0 + cv.x, z1 = a1 + cv.y;
            float m = fmaxf(z0, z1);
            float l2 = m + logf(expf(z0 - m) + expf(z1 - m));
            p.out[node * 2 + 0] = z0 - l2;
            p.out[node * 2 + 1] = z1 - l2;
        }
    }
}

// ---------------------------------------------------------------- launch

extern "C" void kernel_launch(void* const* d_in, const int* in_sizes, int n_in,
                              void* d_out, int out_size, void* d_ws, size_t ws_size,
                              hipStream_t stream) {
    char* wp = (char*)d_ws;
    auto carve = [&](size_t bytes) {
        void* r = (void*)wp;
        wp += ((bytes + 255) / 256) * 256;
        return r;
    };
    MegaP P;
    P.x    = (const float*)d_in[0];
    P.ein  = (const int*)d_in[1];
    P.eout = (const int*)d_in[2];
    P.t    = (const float*)d_in[3];
    P.w0   = (const float*)d_in[4];
    P.b0   = (const float*)d_in[5];
    P.W1i  = (const float*)d_in[6];
    P.b1i  = (const float*)d_in[7];
    P.W2i  = (const float*)d_in[8];
    P.b2i  = (const float*)d_in[9];
    P.w1   = (const float*)d_in[10];
    P.b1   = (const float*)d_in[11];
    P.W1o  = (const float*)d_in[12];
    P.b1o  = (const float*)d_in[13];
    P.W2o  = (const float*)d_in[14];
    P.b2o  = (const float*)d_in[15];
    P.fcw  = (const float*)d_in[16];
    P.fcb  = (const float*)d_in[17];
    P.out  = (float*)d_out;

    P.V     = (float2*)carve((size_t)1024 * 8);
    P.U     = (float2*)carve((size_t)1024 * 8);
    P.beta1 = (float2*)carve(2 * 8);
    P.cvec  = (float2*)carve(8);
    P.r0    = (float2*)carve((size_t)N_NODES * 8);
    P.r1    = (float2*)carve((size_t)N_NODES * 8);
    P.p0    = (float2*)carve((size_t)N_NODES * 8);
    P.p1    = (float2*)carve((size_t)N_NODES * 8);
    P.cnt0  = (int*)carve(N_NODES * 4);
    P.cnt1  = (int*)carve(N_NODES * 4);
    P.rowp0 = (int*)carve((N_NODES + 1) * 4);
    P.rowp1 = (int*)carve((N_NODES + 1) * 4);
    P.fpos0 = (int*)carve(N_NODES * 4);
    P.fpos1 = (int*)carve(N_NODES * 4);
    P.es0   = (int*)carve(N_EDGES * 4);
    P.es1   = (int*)carve(N_EDGES * 4);
    P.dv0   = (float*)carve(N_NODES * 4);
    P.dv1   = (float*)carve(N_NODES * 4);

    void* args[] = {(void*)&P};
    hipLaunchCooperativeKernel((const void*)mega, dim3(NB), dim3(256), args, 0, stream);
}

// Round 10
// 102.159 us; speedup vs baseline: 3.7334x; 3.7334x over previous
//
#include <hip/hip_runtime.h>
#include <math.h>

#define N_NODES 10000
#define N_EDGES 160000
#define D 512

// =============================================================== L1
// blocks [0,256): V_b[k,c] = sum_n W2_b[k][n]*F_b[n][c]  (wave per (b,k))
// blocks [256,1506): degree count (cnt pre-zeroed by memset)

__global__ __launch_bounds__(256) void l1_vproj_deg(
    const float* __restrict__ W2i, const float* __restrict__ W2o,
    const float* __restrict__ fcw, float2* __restrict__ V,
    const int* __restrict__ ein, const int* __restrict__ eout,
    int* __restrict__ cnt0, int* __restrict__ cnt1) {
    int bid = blockIdx.x;
    if (bid < 256) {
        int wv = bid * 4 + (threadIdx.x >> 6);
        int lane = threadIdx.x & 63;
        int b = wv >> 9, k = wv & 511;
        const float* W = b ? W2o : W2i;
        const float* F = fcw + b * 1024;
        float v0 = 0.f, v1 = 0.f;
        for (int n = lane; n < 512; n += 64) {
            float w = W[k * 512 + n];
            v0 += w * F[2 * n];
            v1 += w * F[2 * n + 1];
        }
#pragma unroll
        for (int off = 32; off; off >>= 1) {
            v0 += __shfl_down(v0, off);
            v1 += __shfl_down(v1, off);
        }
        if (lane == 0) V[wv] = make_float2(v0, v1);
    } else {
        int i = (bid - 256) * 256 + threadIdx.x;
        if (i < N_EDGES) atomicAdd(&cnt0[ein[N_EDGES + i]], 1);
        else if (i < 2 * N_EDGES) atomicAdd(&cnt1[eout[i]], 1);
    }
}

// =============================================================== L2
// blocks 0,1: exclusive scan of cnt -> rowp/fpos + dinv (wave-shfl scan)
// blocks [2,259): U_b = W1_b.V_b ; tail wave: beta1, cvec

__global__ __launch_bounds__(256) void l2_scan_uproj(
    const int* __restrict__ cnt0, const int* __restrict__ cnt1,
    int* __restrict__ rowp0, int* __restrict__ rowp1,
    int* __restrict__ fpos0, int* __restrict__ fpos1,
    float* __restrict__ dv0, float* __restrict__ dv1,
    const float* __restrict__ W1i, const float* __restrict__ W1o,
    const float2* __restrict__ V,
    const float* __restrict__ b1i, const float* __restrict__ b1o,
    const float* __restrict__ b2i, const float* __restrict__ b2o,
    const float* __restrict__ fcw, const float* __restrict__ fcb,
    float2* __restrict__ U, float2* __restrict__ beta1, float2* __restrict__ cvec) {
    int bid = blockIdx.x;
    int tid = threadIdx.x;
    int wave = tid >> 6, lane = tid & 63;
    if (bid < 2) {
        __shared__ int wsum[4];
        const int* cnt = bid ? cnt1 : cnt0;
        int* rowp = bid ? rowp1 : rowp0;
        int* fpos = bid ? fpos1 : fpos0;
        float* dv = bid ? dv1 : dv0;
        const int base = tid * 40;
        int sum = 0;
#pragma unroll 4
        for (int j = 0; j < 40; ++j) {
            int i = base + j;
            if (i < N_NODES) sum += cnt[i];
        }
        int incl = sum;
#pragma unroll
        for (int off = 1; off < 64; off <<= 1) {
            int n = __shfl_up(incl, off);
            if (lane >= off) incl += n;
        }
        if (lane == 63) wsum[wave] = incl;
        __syncthreads();
        int wo = 0;
        for (int w = 0; w < wave; ++w) wo += wsum[w];
        int run = wo + incl - sum;
#pragma unroll 4
        for (int j = 0; j < 40; ++j) {
            int i = base + j;
            if (i < N_NODES) {
                rowp[i] = run;
                fpos[i] = run;
                int c = cnt[i];
                dv[i] = rsqrtf((float)c + 1.0f);
                run += c;
            }
        }
        if (tid == 255) rowp[N_NODES] = run;
        return;
    }
    int wv = (bid - 2) * 4 + wave;
    if (wv < 1024) {
        int b = wv >> 9, j = wv & 511;
        const float* W = b ? W1o : W1i;
        const float2* Vb = V + b * 512;
        float u0 = 0.f, u1 = 0.f;
        for (int k = lane; k < 512; k += 64) {
            float w = W[j * 512 + k];
            float2 v = Vb[k];
            u0 += w * v.x;
            u1 += w * v.y;
        }
#pragma unroll
        for (int off = 32; off; off >>= 1) {
            u0 += __shfl_down(u0, off);
            u1 += __shfl_down(u1, off);
        }
        if (lane == 0) U[wv] = make_float2(u0, u1);
    } else if (wv == 1024) {
        float a00 = 0.f, a01 = 0.f, a10 = 0.f, a11 = 0.f, c0 = 0.f, c1 = 0.f;
        for (int k = lane; k < 512; k += 64) {
            float2 v0 = V[k], v1 = V[512 + k];
            a00 += b1i[k] * v0.x;
            a01 += b1i[k] * v0.y;
            a10 += b1o[k] * v1.x;
            a11 += b1o[k] * v1.y;
            c0 += b2i[k] * fcw[2 * k] + b2o[k] * fcw[2 * (512 + k)];
            c1 += b2i[k] * fcw[2 * k + 1] + b2o[k] * fcw[2 * (512 + k) + 1];
        }
#pragma unroll
        for (int off = 32; off; off >>= 1) {
            a00 += __shfl_down(a00, off);
            a01 += __shfl_down(a01, off);
            a10 += __shfl_down(a10, off);
            a11 += __shfl_down(a11, off);
            c0 += __shfl_down(c0, off);
            c1 += __shfl_down(c1, off);
        }
        if (lane == 0) {
            beta1[0] = make_float2(a00, a01);
            beta1[1] = make_float2(a10, a11);
            *cvec = make_float2(c0 + fcb[0], c1 + fcb[1]);
        }
    }
}

// =============================================================== L3
// blocks [0,1250): CSR fill (esrc only)
// blocks [1250,3750): rw_b[i] = dinv_b[i] * (TE_b[i,:] @ U_b)  (wave per node)

__global__ __launch_bounds__(256) void l3_fill_r(
    const int* __restrict__ ein, const int* __restrict__ eout,
    int* __restrict__ fpos0, int* __restrict__ fpos1,
    int* __restrict__ es0, int* __restrict__ es1,
    const float* __restrict__ x, const float* __restrict__ t,
    const float* __restrict__ w0, const float* __restrict__ b0,
    const float* __restrict__ w1, const float* __restrict__ b1,
    const float2* __restrict__ U,
    const float* __restrict__ dv0, const float* __restrict__ dv1,
    float2* __restrict__ r0, float2* __restrict__ r1) {
    int bid = blockIdx.x;
    if (bid < 1250) {
        int i = bid * 256 + threadIdx.x;
        int br = i >= N_EDGES;
        int e = i - br * N_EDGES;
        const int* ei = br ? eout : ein;
        int s = ei[e], d = ei[N_EDGES + e];
        int pos = atomicAdd(&(br ? fpos1 : fpos0)[d], 1);
        (br ? es1 : es0)[pos] = s;
        return;
    }
    int node = (bid - 1250) * 4 + (threadIdx.x >> 6);
    int lane = threadIdx.x & 63;
    int j0 = lane * 8;
    float tv = t[node];
    float4 xa = *(const float4*)&x[(size_t)node * D + j0];
    float4 xb = *(const float4*)&x[(size_t)node * D + j0 + 4];
    float xv[8] = {xa.x, xa.y, xa.z, xa.w, xb.x, xb.y, xb.z, xb.w};
    float s00 = 0.f, s01 = 0.f, s10 = 0.f, s11 = 0.f;
#pragma unroll
    for (int j = 0; j < 8; ++j) {
        float xx = xv[j];
        float te0 = xx + __cosf(tv * w0[j0 + j] + b0[j0 + j]);
        float te1 = xx + __cosf(tv * w1[j0 + j] + b1[j0 + j]);
        float2 u0 = U[j0 + j];
        float2 u1 = U[512 + j0 + j];
        s00 += te0 * u0.x;
        s01 += te0 * u0.y;
        s10 += te1 * u1.x;
        s11 += te1 * u1.y;
    }
#pragma unroll
    for (int off = 32; off; off >>= 1) {
        s00 += __shfl_down(s00, off);
        s01 += __shfl_down(s01, off);
        s10 += __shfl_down(s10, off);
        s11 += __shfl_down(s11, off);
    }
    if (lane == 0) {
        float da = dv0[node], db = dv1[node];
        r0[node] = make_float2(da * s00, da * s01);
        r1[node] = make_float2(db * s10, db * s11);
    }
}

// =============================================================== L4
// pw_b[i] = dvd*beta1_b + dvd^2*(sum_{s in N} rw_b[s] + rw_b[i]),  dvd=dinv_b[i]
// wave per node; lanes 0-31 branch0, 32-63 branch1.

__global__ __launch_bounds__(256) void l4_pgather(
    const float2* __restrict__ r0, const float2* __restrict__ r1,
    const int* __restrict__ rowp0, const int* __restrict__ rowp1,
    const int* __restrict__ es0, const int* __restrict__ es1,
    const float* __restrict__ dv0, const float* __restrict__ dv1,
    const float2* __restrict__ beta1,
    float2* __restrict__ p0, float2* __restrict__ p1) {
    int node = blockIdx.x * 4 + (threadIdx.x >> 6);
    int lane = threadIdx.x & 63;
    int half = lane >> 5, hl = lane & 31;
    const float2* rr = half ? r1 : r0;
    const int* rowp = half ? rowp1 : rowp0;
    const int* es = half ? es1 : es0;
    int beg = rowp[node], end = rowp[node + 1];
    float a0 = 0.f, a1 = 0.f;
    for (int e = beg + hl; e < end; e += 32) {
        float2 v = rr[es[e]];
        a0 += v.x;
        a1 += v.y;
    }
#pragma unroll
    for (int m = 16; m; m >>= 1) {
        a0 += __shfl_xor(a0, m);
        a1 += __shfl_xor(a1, m);
    }
    if (hl == 0) {
        float dvd = (half ? dv1 : dv0)[node];
        float2 rv = rr[node];
        float2 bb = beta1[half];
        float d2 = dvd * dvd;
        (half ? p1 : p0)[node] = make_float2(dvd * bb.x + d2 * (a0 + rv.x),
                                             dvd * bb.y + d2 * (a1 + rv.y));
    }
}

// =============================================================== L5
// z = sum_b dvd_b*(sum_{s in N_b} pw_b[s] + pw_b[i]) + cvec ; log_softmax

__global__ __launch_bounds__(256) void l5_zlsm(
    const float2* __restrict__ p0, const float2* __restrict__ p1,
    const int* __restrict__ rowp0, const int* __restrict__ rowp1,
    const int* __restrict__ es0, const int* __restrict__ es1,
    const float* __restrict__ dv0, const float* __restrict__ dv1,
    const float2* __restrict__ cvec, float* __restrict__ out) {
    int node = blockIdx.x * 4 + (threadIdx.x >> 6);
    int lane = threadIdx.x & 63;
    int half = lane >> 5, hl = lane & 31;
    const float2* pp = half ? p1 : p0;
    const int* rowp = half ? rowp1 : rowp0;
    const int* es = half ? es1 : es0;
    int beg = rowp[node], end = rowp[node + 1];
    float a0 = 0.f, a1 = 0.f;
    for (int e = beg + hl; e < end; e += 32) {
        float2 v = pp[es[e]];
        a0 += v.x;
        a1 += v.y;
    }
#pragma unroll
    for (int m = 16; m; m >>= 1) {
        a0 += __shfl_xor(a0, m);
        a1 += __shfl_xor(a1, m);
    }
    float dvd = (half ? dv1 : dv0)[node];
    float2 ps = pp[node];
    a0 = dvd * (a0 + ps.x);
    a1 = dvd * (a1 + ps.y);
    a0 += __shfl_xor(a0, 32);
    a1 += __shfl_xor(a1, 32);
    if (lane == 0) {
        float2 cv = *cvec;
        float z0 = a0 + cv.x, z1 = a1 + cv.y;
        float m = fmaxf(z0, z1);
        float l2 = m + logf(expf(z0 - m) + expf(z1 - m));
        out[node * 2 + 0] = z0 - l2;
        out[node * 2 + 1] = z1 - l2;
    }
}

// ---------------------------------------------------------------- launch

extern "C" void kernel_launch(void* const* d_in, const int* in_sizes, int n_in,
                              void* d_out, int out_size, void* d_ws, size_t ws_size,
                              hipStream_t stream) {
    const float* x        = (const float*)d_in[0];
    const int*   ein      = (const int*)d_in[1];
    const int*   eout     = (const int*)d_in[2];
    const float* t        = (const float*)d_in[3];
    const float* te_w[2]  = {(const float*)d_in[4], (const float*)d_in[10]};
    const float* te_b[2]  = {(const float*)d_in[5], (const float*)d_in[11]};
    const float* W1[2]    = {(const float*)d_in[6], (const float*)d_in[12]};
    const float* b1[2]    = {(const float*)d_in[7], (const float*)d_in[13]};
    const float* W2[2]    = {(const float*)d_in[8], (const float*)d_in[14]};
    const float* b2[2]    = {(const float*)d_in[9], (const float*)d_in[15]};
    const float* fc_w     = (const float*)d_in[16];
    const float* fc_b     = (const float*)d_in[17];
    float* out = (float*)d_out;

    char* wp = (char*)d_ws;
    auto carve = [&](size_t bytes) {
        void* r = (void*)wp;
        wp += ((bytes + 255) / 256) * 256;
        return r;
    };
    float2* V     = (float2*)carve((size_t)1024 * 8);
    float2* U     = (float2*)carve((size_t)1024 * 8);
    float2* beta1 = (float2*)carve(2 * 8);
    float2* cvec  = (float2*)carve(8);
    float2* rbuf[2];
    rbuf[0] = (float2*)carve((size_t)N_NODES * 8);
    rbuf[1] = (float2*)carve((size_t)N_NODES * 8);
    float2* pbuf[2];
    pbuf[0] = (float2*)carve((size_t)N_NODES * 8);
    pbuf[1] = (float2*)carve((size_t)N_NODES * 8);
    int* cnt = (int*)carve((size_t)2 * N_NODES * 4);  // cnt0|cnt1 contiguous
    int* cnt0 = cnt, *cnt1 = cnt + N_NODES;
    int*   rowp[2]; rowp[0] = (int*)carve((N_NODES + 1) * 4); rowp[1] = (int*)carve((N_NODES + 1) * 4);
    int*   fpos[2]; fpos[0] = (int*)carve(N_NODES * 4);       fpos[1] = (int*)carve(N_NODES * 4);
    int*   esrc[2]; esrc[0] = (int*)carve(N_EDGES * 4);       esrc[1] = (int*)carve(N_EDGES * 4);
    float* dinv[2]; dinv[0] = (float*)carve(N_NODES * 4);     dinv[1] = (float*)carve(N_NODES * 4);

    hipMemsetAsync(cnt, 0, (size_t)2 * N_NODES * 4, stream);
    l1_vproj_deg<<<256 + 1250, 256, 0, stream>>>(W2[0], W2[1], fc_w, V,
                                                 ein, eout, cnt0, cnt1);
    l2_scan_uproj<<<259, 256, 0, stream>>>(cnt0, cnt1, rowp[0], rowp[1],
                                           fpos[0], fpos[1], dinv[0], dinv[1],
                                           W1[0], W1[1], V, b1[0], b1[1],
                                           b2[0], b2[1], fc_w, fc_b, U, beta1, cvec);
    l3_fill_r<<<1250 + 2500, 256, 0, stream>>>(ein, eout, fpos[0], fpos[1],
                                               esrc[0], esrc[1], x, t,
                                               te_w[0], te_b[0], te_w[1], te_b[1],
                                               U, dinv[0], dinv[1], rbuf[0], rbuf[1]);
    l4_pgather<<<2500, 256, 0, stream>>>(rbuf[0], rbuf[1], rowp[0], rowp[1],
                                         esrc[0], esrc[1], dinv[0], dinv[1],
                                         beta1, pbuf[0], pbuf[1]);
    l5_zlsm<<<2500, 256, 0, stream>>>(pbuf[0], pbuf[1], rowp[0], rowp[1],
                                      esrc[0], esrc[1], dinv[0], dinv[1], cvec, out);
}

// Round 11
// 100.170 us; speedup vs baseline: 3.8075x; 1.0199x over previous
//
#include <hip/hip_runtime.h>
#include <math.h>

#define N_NODES 10000
#define N_EDGES 160000
#define D 512

// =============================================================== L0
// blocks [0,256): V_b[k,c] = sum_n W2_b[k][n]*F_b[n][c]  (wave per (b,k))
// blocks [256,335): zero cnt0|cnt1 (contiguous 2*N ints)

__global__ __launch_bounds__(256) void l0_vproj_zero(
    const float* __restrict__ W2i, const float* __restrict__ W2o,
    const float* __restrict__ fcw, float2* __restrict__ V,
    int* __restrict__ cnt) {
    int bid = blockIdx.x;
    if (bid < 256) {
        int wv = bid * 4 + (threadIdx.x >> 6);
        int lane = threadIdx.x & 63;
        int b = wv >> 9, k = wv & 511;
        const float* W = b ? W2o : W2i;
        const float* F = fcw + b * 1024;
        float v0 = 0.f, v1 = 0.f;
        for (int n = lane; n < 512; n += 64) {
            float w = W[k * 512 + n];
            v0 += w * F[2 * n];
            v1 += w * F[2 * n + 1];
        }
#pragma unroll
        for (int off = 32; off; off >>= 1) {
            v0 += __shfl_down(v0, off);
            v1 += __shfl_down(v1, off);
        }
        if (lane == 0) V[wv] = make_float2(v0, v1);
    } else {
        int i = (bid - 256) * 256 + threadIdx.x;
        if (i < 2 * N_NODES) cnt[i] = 0;
    }
}

// =============================================================== L1
// blocks [0,1250): degree count
// blocks [1250,1508): U_b = W1_b.V_b ; tail wave: beta1, cvec

__global__ __launch_bounds__(256) void l1_deg_uproj(
    const int* __restrict__ ein, const int* __restrict__ eout,
    int* __restrict__ cnt0, int* __restrict__ cnt1,
    const float* __restrict__ W1i, const float* __restrict__ W1o,
    const float2* __restrict__ V,
    const float* __restrict__ b1i, const float* __restrict__ b1o,
    const float* __restrict__ b2i, const float* __restrict__ b2o,
    const float* __restrict__ fcw, const float* __restrict__ fcb,
    float2* __restrict__ U, float2* __restrict__ beta1, float2* __restrict__ cvec) {
    int bid = blockIdx.x;
    if (bid < 1250) {
        int i = bid * 256 + threadIdx.x;
        if (i < N_EDGES) atomicAdd(&cnt0[ein[N_EDGES + i]], 1);
        else if (i < 2 * N_EDGES) atomicAdd(&cnt1[eout[i]], 1);
        return;
    }
    int wv = (bid - 1250) * 4 + (threadIdx.x >> 6);
    int lane = threadIdx.x & 63;
    if (wv < 1024) {
        int b = wv >> 9, j = wv & 511;
        const float* W = b ? W1o : W1i;
        const float2* Vb = V + b * 512;
        float u0 = 0.f, u1 = 0.f;
        for (int k = lane; k < 512; k += 64) {
            float w = W[j * 512 + k];
            float2 v = Vb[k];
            u0 += w * v.x;
            u1 += w * v.y;
        }
#pragma unroll
        for (int off = 32; off; off >>= 1) {
            u0 += __shfl_down(u0, off);
            u1 += __shfl_down(u1, off);
        }
        if (lane == 0) U[wv] = make_float2(u0, u1);
    } else if (wv == 1024) {
        float a00 = 0.f, a01 = 0.f, a10 = 0.f, a11 = 0.f, c0 = 0.f, c1 = 0.f;
        for (int k = lane; k < 512; k += 64) {
            float2 v0 = V[k], v1 = V[512 + k];
            a00 += b1i[k] * v0.x;
            a01 += b1i[k] * v0.y;
            a10 += b1o[k] * v1.x;
            a11 += b1o[k] * v1.y;
            c0 += b2i[k] * fcw[2 * k] + b2o[k] * fcw[2 * (512 + k)];
            c1 += b2i[k] * fcw[2 * k + 1] + b2o[k] * fcw[2 * (512 + k) + 1];
        }
#pragma unroll
        for (int off = 32; off; off >>= 1) {
            a00 += __shfl_down(a00, off);
            a01 += __shfl_down(a01, off);
            a10 += __shfl_down(a10, off);
            a11 += __shfl_down(a11, off);
            c0 += __shfl_down(c0, off);
            c1 += __shfl_down(c1, off);
        }
        if (lane == 0) {
            beta1[0] = make_float2(a00, a01);
            beta1[1] = make_float2(a10, a11);
            *cvec = make_float2(c0 + fcb[0], c1 + fcb[1]);
        }
    }
}

// =============================================================== L2
// 2 blocks: exclusive scan of cnt -> rowp/fpos + dinv (wave-shfl scan)

__global__ __launch_bounds__(256) void l2_scan(
    const int* __restrict__ cnt0, const int* __restrict__ cnt1,
    int* __restrict__ rowp0, int* __restrict__ rowp1,
    int* __restrict__ fpos0, int* __restrict__ fpos1,
    float* __restrict__ dv0, float* __restrict__ dv1) {
    int bid = blockIdx.x, tid = threadIdx.x;
    int wave = tid >> 6, lane = tid & 63;
    __shared__ int wsum[4];
    const int* cnt = bid ? cnt1 : cnt0;
    int* rowp = bid ? rowp1 : rowp0;
    int* fpos = bid ? fpos1 : fpos0;
    float* dv = bid ? dv1 : dv0;
    const int base = tid * 40;
    int sum = 0;
#pragma unroll 4
    for (int j = 0; j < 40; ++j) {
        int i = base + j;
        if (i < N_NODES) sum += cnt[i];
    }
    int incl = sum;
#pragma unroll
    for (int off = 1; off < 64; off <<= 1) {
        int n = __shfl_up(incl, off);
        if (lane >= off) incl += n;
    }
    if (lane == 63) wsum[wave] = incl;
    __syncthreads();
    int wo = 0;
    for (int w = 0; w < wave; ++w) wo += wsum[w];
    int run = wo + incl - sum;
#pragma unroll 4
    for (int j = 0; j < 40; ++j) {
        int i = base + j;
        if (i < N_NODES) {
            rowp[i] = run;
            fpos[i] = run;
            int c = cnt[i];
            dv[i] = rsqrtf((float)c + 1.0f);
            run += c;
        }
    }
    if (tid == 255) rowp[N_NODES] = run;
}

// =============================================================== L3
// blocks [0,1250): CSR fill (esrc only)
// blocks [1250,3750): rw_b[i] = dinv_b[i] * (TE_b[i,:] @ U_b)  (wave per node)

__global__ __launch_bounds__(256) void l3_fill_r(
    const int* __restrict__ ein, const int* __restrict__ eout,
    int* __restrict__ fpos0, int* __restrict__ fpos1,
    int* __restrict__ es0, int* __restrict__ es1,
    const float* __restrict__ x, const float* __restrict__ t,
    const float* __restrict__ w0, const float* __restrict__ b0,
    const float* __restrict__ w1, const float* __restrict__ b1,
    const float2* __restrict__ U,
    const float* __restrict__ dv0, const float* __restrict__ dv1,
    float2* __restrict__ r0, float2* __restrict__ r1) {
    int bid = blockIdx.x;
    if (bid < 1250) {
        int i = bid * 256 + threadIdx.x;
        int br = i >= N_EDGES;
        int e = i - br * N_EDGES;
        const int* ei = br ? eout : ein;
        int s = ei[e], d = ei[N_EDGES + e];
        int pos = atomicAdd(&(br ? fpos1 : fpos0)[d], 1);
        (br ? es1 : es0)[pos] = s;
        return;
    }
    int node = (bid - 1250) * 4 + (threadIdx.x >> 6);
    int lane = threadIdx.x & 63;
    int j0 = lane * 8;
    float tv = t[node];
    float4 xa = *(const float4*)&x[(size_t)node * D + j0];
    float4 xb = *(const float4*)&x[(size_t)node * D + j0 + 4];
    float xv[8] = {xa.x, xa.y, xa.z, xa.w, xb.x, xb.y, xb.z, xb.w};
    float s00 = 0.f, s01 = 0.f, s10 = 0.f, s11 = 0.f;
#pragma unroll
    for (int j = 0; j < 8; ++j) {
        float xx = xv[j];
        float te0 = xx + __cosf(tv * w0[j0 + j] + b0[j0 + j]);
        float te1 = xx + __cosf(tv * w1[j0 + j] + b1[j0 + j]);
        float2 u0 = U[j0 + j];
        float2 u1 = U[512 + j0 + j];
        s00 += te0 * u0.x;
        s01 += te0 * u0.y;
        s10 += te1 * u1.x;
        s11 += te1 * u1.y;
    }
#pragma unroll
    for (int off = 32; off; off >>= 1) {
        s00 += __shfl_down(s00, off);
        s01 += __shfl_down(s01, off);
        s10 += __shfl_down(s10, off);
        s11 += __shfl_down(s11, off);
    }
    if (lane == 0) {
        float da = dv0[node], db = dv1[node];
        r0[node] = make_float2(da * s00, da * s01);
        r1[node] = make_float2(db * s10, db * s11);
    }
}

// =============================================================== L4
// pw_b[i] = dvd*beta1_b + dvd^2*(sum_{s in N} rw_b[s] + rw_b[i])

__global__ __launch_bounds__(256) void l4_pgather(
    const float2* __restrict__ r0, const float2* __restrict__ r1,
    const int* __restrict__ rowp0, const int* __restrict__ rowp1,
    const int* __restrict__ es0, const int* __restrict__ es1,
    const float* __restrict__ dv0, const float* __restrict__ dv1,
    const float2* __restrict__ beta1,
    float2* __restrict__ p0, float2* __restrict__ p1) {
    int node = blockIdx.x * 4 + (threadIdx.x >> 6);
    int lane = threadIdx.x & 63;
    int half = lane >> 5, hl = lane & 31;
    const float2* rr = half ? r1 : r0;
    const int* rowp = half ? rowp1 : rowp0;
    const int* es = half ? es1 : es0;
    int beg = rowp[node], end = rowp[node + 1];
    float a0 = 0.f, a1 = 0.f;
    for (int e = beg + hl; e < end; e += 32) {
        float2 v = rr[es[e]];
        a0 += v.x;
        a1 += v.y;
    }
#pragma unroll
    for (int m = 16; m; m >>= 1) {
        a0 += __shfl_xor(a0, m);
        a1 += __shfl_xor(a1, m);
    }
    if (hl == 0) {
        float dvd = (half ? dv1 : dv0)[node];
        float2 rv = rr[node];
        float2 bb = beta1[half];
        float d2 = dvd * dvd;
        (half ? p1 : p0)[node] = make_float2(dvd * bb.x + d2 * (a0 + rv.x),
                                             dvd * bb.y + d2 * (a1 + rv.y));
    }
}

// =============================================================== L5
// z = sum_b dvd_b*(sum_{s in N_b} pw_b[s] + pw_b[i]) + cvec ; log_softmax

__global__ __launch_bounds__(256) void l5_zlsm(
    const float2* __restrict__ p0, const float2* __restrict__ p1,
    const int* __restrict__ rowp0, const int* __restrict__ rowp1,
    const int* __restrict__ es0, const int* __restrict__ es1,
    const float* __restrict__ dv0, const float* __restrict__ dv1,
    const float2* __restrict__ cvec, float* __restrict__ out) {
    int node = blockIdx.x * 4 + (threadIdx.x >> 6);
    int lane = threadIdx.x & 63;
    int half = lane >> 5, hl = lane & 31;
    const float2* pp = half ? p1 : p0;
    const int* rowp = half ? rowp1 : rowp0;
    const int* es = half ? es1 : es0;
    int beg = rowp[node], end = rowp[node + 1];
    float a0 = 0.f, a1 = 0.f;
    for (int e = beg + hl; e < end; e += 32) {
        float2 v = pp[es[e]];
        a0 += v.x;
        a1 += v.y;
    }
#pragma unroll
    for (int m = 16; m; m >>= 1) {
        a0 += __shfl_xor(a0, m);
        a1 += __shfl_xor(a1, m);
    }
    float dvd = (half ? dv1 : dv0)[node];
    float2 ps = pp[node];
    a0 = dvd * (a0 + ps.x);
    a1 = dvd * (a1 + ps.y);
    a0 += __shfl_xor(a0, 32);
    a1 += __shfl_xor(a1, 32);
    if (lane == 0) {
        float2 cv = *cvec;
        float z0 = a0 + cv.x, z1 = a1 + cv.y;
        float m = fmaxf(z0, z1);
        float l2 = m + logf(expf(z0 - m) + expf(z1 - m));
        out[node * 2 + 0] = z0 - l2;
        out[node * 2 + 1] = z1 - l2;
    }
}

// ---------------------------------------------------------------- launch

extern "C" void kernel_launch(void* const* d_in, const int* in_sizes, int n_in,
                              void* d_out, int out_size, void* d_ws, size_t ws_size,
                              hipStream_t stream) {
    const float* x        = (const float*)d_in[0];
    const int*   ein      = (const int*)d_in[1];
    const int*   eout     = (const int*)d_in[2];
    const float* t        = (const float*)d_in[3];
    const float* te_w[2]  = {(const float*)d_in[4], (const float*)d_in[10]};
    const float* te_b[2]  = {(const float*)d_in[5], (const float*)d_in[11]};
    const float* W1[2]    = {(const float*)d_in[6], (const float*)d_in[12]};
    const float* b1[2]    = {(const float*)d_in[7], (const float*)d_in[13]};
    const float* W2[2]    = {(const float*)d_in[8], (const float*)d_in[14]};
    const float* b2[2]    = {(const float*)d_in[9], (const float*)d_in[15]};
    const float* fc_w     = (const float*)d_in[16];
    const float* fc_b     = (const float*)d_in[17];
    float* out = (float*)d_out;

    char* wp = (char*)d_ws;
    auto carve = [&](size_t bytes) {
        void* r = (void*)wp;
        wp += ((bytes + 255) / 256) * 256;
        return r;
    };
    float2* V     = (float2*)carve((size_t)1024 * 8);
    float2* U     = (float2*)carve((size_t)1024 * 8);
    float2* beta1 = (float2*)carve(2 * 8);
    float2* cvec  = (float2*)carve(8);
    float2* rbuf[2];
    rbuf[0] = (float2*)carve((size_t)N_NODES * 8);
    rbuf[1] = (float2*)carve((size_t)N_NODES * 8);
    float2* pbuf[2];
    pbuf[0] = (float2*)carve((size_t)N_NODES * 8);
    pbuf[1] = (float2*)carve((size_t)N_NODES * 8);
    int* cnt = (int*)carve((size_t)2 * N_NODES * 4);  // cnt0|cnt1 contiguous
    int *cnt0 = cnt, *cnt1 = cnt + N_NODES;
    int*   rowp[2]; rowp[0] = (int*)carve((N_NODES + 1) * 4); rowp[1] = (int*)carve((N_NODES + 1) * 4);
    int*   fpos[2]; fpos[0] = (int*)carve(N_NODES * 4);       fpos[1] = (int*)carve(N_NODES * 4);
    int*   esrc[2]; esrc[0] = (int*)carve(N_EDGES * 4);       esrc[1] = (int*)carve(N_EDGES * 4);
    float* dinv[2]; dinv[0] = (float*)carve(N_NODES * 4);     dinv[1] = (float*)carve(N_NODES * 4);

    l0_vproj_zero<<<335, 256, 0, stream>>>(W2[0], W2[1], fc_w, V, cnt);
    l1_deg_uproj<<<1508, 256, 0, stream>>>(ein, eout, cnt0, cnt1,
                                           W1[0], W1[1], V, b1[0], b1[1],
                                           b2[0], b2[1], fc_w, fc_b, U, beta1, cvec);
    l2_scan<<<2, 256, 0, stream>>>(cnt0, cnt1, rowp[0], rowp[1],
                                   fpos[0], fpos[1], dinv[0], dinv[1]);
    l3_fill_r<<<1250 + 2500, 256, 0, stream>>>(ein, eout, fpos[0], fpos[1],
                                               esrc[0], esrc[1], x, t,
                                               te_w[0], te_b[0], te_w[1], te_b[1],
                                               U, dinv[0], dinv[1], rbuf[0], rbuf[1]);
    l4_pgather<<<2500, 256, 0, stream>>>(rbuf[0], rbuf[1], rowp[0], rowp[1],
                                         esrc[0], esrc[1], dinv[0], dinv[1],
                                         beta1, pbuf[0], pbuf[1]);
    l5_zlsm<<<2500, 256, 0, stream>>>(pbuf[0], pbuf[1], rowp[0], rowp[1],
                                      esrc[0], esrc[1], dinv[0], dinv[1], cvec, out);
}

// Round 12
// 52.686 us; speedup vs baseline: 7.2391x; 1.9013x over previous
//
#include <hip/hip_runtime.h>
#include <math.h>

#define N_NODES 10000
#define N_EDGES 160000
#define D 512
#define SLOTS 64

// =============================================================== K1
// blocks [0,256): V_b[k,c] = sum_n W2_b[k][n]*F_b[n][c]  (wave per (b,k))
// blocks [256,335): zero fpos0|fpos1 (contiguous 2*N ints)

__global__ __launch_bounds__(256) void k1_vproj_zero(
    const float* __restrict__ W2i, const float* __restrict__ W2o,
    const float* __restrict__ fcw, float2* __restrict__ V,
    int* __restrict__ fpos) {
    int bid = blockIdx.x;
    if (bid < 256) {
        int wv = bid * 4 + (threadIdx.x >> 6);
        int lane = threadIdx.x & 63;
        int b = wv >> 9, k = wv & 511;
        const float* W = b ? W2o : W2i;
        const float* F = fcw + b * 1024;
        float v0 = 0.f, v1 = 0.f;
        for (int n = lane; n < 512; n += 64) {
            float w = W[k * 512 + n];
            v0 += w * F[2 * n];
            v1 += w * F[2 * n + 1];
        }
#pragma unroll
        for (int off = 32; off; off >>= 1) {
            v0 += __shfl_down(v0, off);
            v1 += __shfl_down(v1, off);
        }
        if (lane == 0) V[wv] = make_float2(v0, v1);
    } else {
        int i = (bid - 256) * 256 + threadIdx.x;
        if (i < 2 * N_NODES) fpos[i] = 0;
    }
}

// =============================================================== K2
// blocks [0,1250): slot-CSR fill (fpos counts degree as side effect)
// blocks [1250,1508): U_b = W1_b.V_b ; tail wave: beta1, cvec

__global__ __launch_bounds__(256) void k2_fill_uproj(
    const int* __restrict__ ein, const int* __restrict__ eout,
    int* __restrict__ fpos0, int* __restrict__ fpos1,
    int* __restrict__ es0, int* __restrict__ es1,
    const float* __restrict__ W1i, const float* __restrict__ W1o,
    const float2* __restrict__ V,
    const float* __restrict__ b1i, const float* __restrict__ b1o,
    const float* __restrict__ b2i, const float* __restrict__ b2o,
    const float* __restrict__ fcw, const float* __restrict__ fcb,
    float2* __restrict__ U, float2* __restrict__ beta1, float2* __restrict__ cvec) {
    int bid = blockIdx.x;
    if (bid < 1250) {
        int i = bid * 256 + threadIdx.x;
        int br = i >= N_EDGES;
        int e = i - br * N_EDGES;
        const int* ei = br ? eout : ein;
        int s = ei[e], d = ei[N_EDGES + e];
        int pos = atomicAdd(&(br ? fpos1 : fpos0)[d], 1);
        if (pos < SLOTS) (br ? es1 : es0)[d * SLOTS + pos] = s;
        return;
    }
    int wv = (bid - 1250) * 4 + (threadIdx.x >> 6);
    int lane = threadIdx.x & 63;
    if (wv < 1024) {
        int b = wv >> 9, j = wv & 511;
        const float* W = b ? W1o : W1i;
        const float2* Vb = V + b * 512;
        float u0 = 0.f, u1 = 0.f;
        for (int k = lane; k < 512; k += 64) {
            float w = W[j * 512 + k];
            float2 v = Vb[k];
            u0 += w * v.x;
            u1 += w * v.y;
        }
#pragma unroll
        for (int off = 32; off; off >>= 1) {
            u0 += __shfl_down(u0, off);
            u1 += __shfl_down(u1, off);
        }
        if (lane == 0) U[wv] = make_float2(u0, u1);
    } else if (wv == 1024) {
        float a00 = 0.f, a01 = 0.f, a10 = 0.f, a11 = 0.f, c0 = 0.f, c1 = 0.f;
        for (int k = lane; k < 512; k += 64) {
            float2 v0 = V[k], v1 = V[512 + k];
            a00 += b1i[k] * v0.x;
            a01 += b1i[k] * v0.y;
            a10 += b1o[k] * v1.x;
            a11 += b1o[k] * v1.y;
            c0 += b2i[k] * fcw[2 * k] + b2o[k] * fcw[2 * (512 + k)];
            c1 += b2i[k] * fcw[2 * k + 1] + b2o[k] * fcw[2 * (512 + k) + 1];
        }
#pragma unroll
        for (int off = 32; off; off >>= 1) {
            a00 += __shfl_down(a00, off);
            a01 += __shfl_down(a01, off);
            a10 += __shfl_down(a10, off);
            a11 += __shfl_down(a11, off);
            c0 += __shfl_down(c0, off);
            c1 += __shfl_down(c1, off);
        }
        if (lane == 0) {
            beta1[0] = make_float2(a00, a01);
            beta1[1] = make_float2(a10, a11);
            *cvec = make_float2(c0 + fcb[0], c1 + fcb[1]);
        }
    }
}

// =============================================================== K3
// rw_b[i] = dinv_b[i] * (TE_b[i,:] @ U_b), dinv from slot counts (wave/node)

__global__ __launch_bounds__(256) void k3_r(
    const float* __restrict__ x, const float* __restrict__ t,
    const float* __restrict__ w0, const float* __restrict__ b0,
    const float* __restrict__ w1, const float* __restrict__ b1,
    const float2* __restrict__ U,
    const int* __restrict__ fpos0, const int* __restrict__ fpos1,
    float2* __restrict__ r0, float2* __restrict__ r1,
    float* __restrict__ dv0, float* __restrict__ dv1) {
    int node = blockIdx.x * 4 + (threadIdx.x >> 6);
    int lane = threadIdx.x & 63;
    int j0 = lane * 8;
    float tv = t[node];
    float4 xa = *(const float4*)&x[(size_t)node * D + j0];
    float4 xb = *(const float4*)&x[(size_t)node * D + j0 + 4];
    float xv[8] = {xa.x, xa.y, xa.z, xa.w, xb.x, xb.y, xb.z, xb.w};
    float s00 = 0.f, s01 = 0.f, s10 = 0.f, s11 = 0.f;
#pragma unroll
    for (int j = 0; j < 8; ++j) {
        float xx = xv[j];
        float te0 = xx + __cosf(tv * w0[j0 + j] + b0[j0 + j]);
        float te1 = xx + __cosf(tv * w1[j0 + j] + b1[j0 + j]);
        float2 u0 = U[j0 + j];
        float2 u1 = U[512 + j0 + j];
        s00 += te0 * u0.x;
        s01 += te0 * u0.y;
        s10 += te1 * u1.x;
        s11 += te1 * u1.y;
    }
#pragma unroll
    for (int off = 32; off; off >>= 1) {
        s00 += __shfl_down(s00, off);
        s01 += __shfl_down(s01, off);
        s10 += __shfl_down(s10, off);
        s11 += __shfl_down(s11, off);
    }
    if (lane == 0) {
        float da = rsqrtf((float)fpos0[node] + 1.0f);
        float db = rsqrtf((float)fpos1[node] + 1.0f);
        dv0[node] = da;
        dv1[node] = db;
        r0[node] = make_float2(da * s00, da * s01);
        r1[node] = make_float2(db * s10, db * s11);
    }
}

// =============================================================== K4
// pw_b[i] = dvd*beta1_b + dvd^2*(sum_{s in N} rw_b[s] + rw_b[i])
// wave per node; lanes 0-31 branch0, 32-63 branch1; slots contiguous.

__global__ __launch_bounds__(256) void k4_pgather(
    const float2* __restrict__ r0, const float2* __restrict__ r1,
    const int* __restrict__ fpos0, const int* __restrict__ fpos1,
    const int* __restrict__ es0, const int* __restrict__ es1,
    const float* __restrict__ dv0, const float* __restrict__ dv1,
    const float2* __restrict__ beta1,
    float2* __restrict__ p0, float2* __restrict__ p1) {
    int node = blockIdx.x * 4 + (threadIdx.x >> 6);
    int lane = threadIdx.x & 63;
    int half = lane >> 5, hl = lane & 31;
    const float2* rr = half ? r1 : r0;
    const int* es = half ? es1 : es0;
    int cnt = (half ? fpos1 : fpos0)[node];
    if (cnt > SLOTS) cnt = SLOTS;
    float a0 = 0.f, a1 = 0.f;
    for (int j = hl; j < cnt; j += 32) {
        float2 v = rr[es[node * SLOTS + j]];
        a0 += v.x;
        a1 += v.y;
    }
#pragma unroll
    for (int m = 16; m; m >>= 1) {
        a0 += __shfl_xor(a0, m);
        a1 += __shfl_xor(a1, m);
    }
    if (hl == 0) {
        float dvd = (half ? dv1 : dv0)[node];
        float2 rv = rr[node];
        float2 bb = beta1[half];
        float d2 = dvd * dvd;
        (half ? p1 : p0)[node] = make_float2(dvd * bb.x + d2 * (a0 + rv.x),
                                             dvd * bb.y + d2 * (a1 + rv.y));
    }
}

// =============================================================== K5
// z = sum_b dvd_b*(sum_{s in N_b} pw_b[s] + pw_b[i]) + cvec ; log_softmax

__global__ __launch_bounds__(256) void k5_zlsm(
    const float2* __restrict__ p0, const float2* __restrict__ p1,
    const int* __restrict__ fpos0, const int* __restrict__ fpos1,
    const int* __restrict__ es0, const int* __restrict__ es1,
    const float* __restrict__ dv0, const float* __restrict__ dv1,
    const float2* __restrict__ cvec, float* __restrict__ out) {
    int node = blockIdx.x * 4 + (threadIdx.x >> 6);
    int lane = threadIdx.x & 63;
    int half = lane >> 5, hl = lane & 31;
    const float2* pp = half ? p1 : p0;
    const int* es = half ? es1 : es0;
    int cnt = (half ? fpos1 : fpos0)[node];
    if (cnt > SLOTS) cnt = SLOTS;
    float a0 = 0.f, a1 = 0.f;
    for (int j = hl; j < cnt; j += 32) {
        float2 v = pp[es[node * SLOTS + j]];
        a0 += v.x;
        a1 += v.y;
    }
#pragma unroll
    for (int m = 16; m; m >>= 1) {
        a0 += __shfl_xor(a0, m);
        a1 += __shfl_xor(a1, m);
    }
    float dvd = (half ? dv1 : dv0)[node];
    float2 ps = pp[node];
    a0 = dvd * (a0 + ps.x);
    a1 = dvd * (a1 + ps.y);
    a0 += __shfl_xor(a0, 32);
    a1 += __shfl_xor(a1, 32);
    if (lane == 0) {
        float2 cv = *cvec;
        float z0 = a0 + cv.x, z1 = a1 + cv.y;
        float m = fmaxf(z0, z1);
        float l2 = m + logf(expf(z0 - m) + expf(z1 - m));
        out[node * 2 + 0] = z0 - l2;
        out[node * 2 + 1] = z1 - l2;
    }
}

// ---------------------------------------------------------------- launch

extern "C" void kernel_launch(void* const* d_in, const int* in_sizes, int n_in,
                              void* d_out, int out_size, void* d_ws, size_t ws_size,
                              hipStream_t stream) {
    const float* x        = (const float*)d_in[0];
    const int*   ein      = (const int*)d_in[1];
    const int*   eout     = (const int*)d_in[2];
    const float* t        = (const float*)d_in[3];
    const float* te_w[2]  = {(const float*)d_in[4], (const float*)d_in[10]};
    const float* te_b[2]  = {(const float*)d_in[5], (const float*)d_in[11]};
    const float* W1[2]    = {(const float*)d_in[6], (const float*)d_in[12]};
    const float* b1[2]    = {(const float*)d_in[7], (const float*)d_in[13]};
    const float* W2[2]    = {(const float*)d_in[8], (const float*)d_in[14]};
    const float* b2[2]    = {(const float*)d_in[9], (const float*)d_in[15]};
    const float* fc_w     = (const float*)d_in[16];
    const float* fc_b     = (const float*)d_in[17];
    float* out = (float*)d_out;

    char* wp = (char*)d_ws;
    auto carve = [&](size_t bytes) {
        void* r = (void*)wp;
        wp += ((bytes + 255) / 256) * 256;
        return r;
    };
    float2* V     = (float2*)carve((size_t)1024 * 8);
    float2* U     = (float2*)carve((size_t)1024 * 8);
    float2* beta1 = (float2*)carve(2 * 8);
    float2* cvec  = (float2*)carve(8);
    float2* rbuf[2];
    rbuf[0] = (float2*)carve((size_t)N_NODES * 8);
    rbuf[1] = (float2*)carve((size_t)N_NODES * 8);
    float2* pbuf[2];
    pbuf[0] = (float2*)carve((size_t)N_NODES * 8);
    pbuf[1] = (float2*)carve((size_t)N_NODES * 8);
    int* fpos = (int*)carve((size_t)2 * N_NODES * 4);  // fpos0|fpos1 contiguous
    int *fpos0 = fpos, *fpos1 = fpos + N_NODES;
    int* esrc[2];
    esrc[0] = (int*)carve((size_t)N_NODES * SLOTS * 4);
    esrc[1] = (int*)carve((size_t)N_NODES * SLOTS * 4);
    float* dinv[2];
    dinv[0] = (float*)carve(N_NODES * 4);
    dinv[1] = (float*)carve(N_NODES * 4);

    k1_vproj_zero<<<335, 256, 0, stream>>>(W2[0], W2[1], fc_w, V, fpos);
    k2_fill_uproj<<<1508, 256, 0, stream>>>(ein, eout, fpos0, fpos1,
                                            esrc[0], esrc[1],
                                            W1[0], W1[1], V, b1[0], b1[1],
                                            b2[0], b2[1], fc_w, fc_b, U, beta1, cvec);
    k3_r<<<2500, 256, 0, stream>>>(x, t, te_w[0], te_b[0], te_w[1], te_b[1],
                                   U, fpos0, fpos1, rbuf[0], rbuf[1],
                                   dinv[0], dinv[1]);
    k4_pgather<<<2500, 256, 0, stream>>>(rbuf[0], rbuf[1], fpos0, fpos1,
                                         esrc[0], esrc[1], dinv[0], dinv[1],
                                         beta1, pbuf[0], pbuf[1]);
    k5_zlsm<<<2500, 256, 0, stream>>>(pbuf[0], pbuf[1], fpos0, fpos1,
                                      esrc[0], esrc[1], dinv[0], dinv[1], cvec, out);
}